// Round 8
// baseline (91.061 us; speedup 1.0000x reference)
//
#include <hip/hip_runtime.h>
#include <hip/hip_cooperative_groups.h>

namespace cg = cooperative_groups;

#define EPSF 1e-7f

__device__ __forceinline__ float rcp_fast(float x) { return __builtin_amdgcn_rcpf(x); }

// LDS float4-chunk swizzle: spreads strided row reads across bank groups.
__device__ __forceinline__ int swz(int r, int c) { return r * 16 + (c ^ ((r >> 2) & 7)); }

__device__ __forceinline__ float dot4(float4 v) {
    return v.x * v.x + v.y * v.y + v.z * v.z + v.w * v.w;
}

// Single cooperative kernel, 512 blocks x 256 threads (2 blocks/CU co-resident).
// Phase 1: pair map  (block = 32i x 64j tile; lane-pair micro-tile) -> T, alphaPart
// grid.sync()
// Phase 2: v = T[i,:]*X + alpha*x_i; expmap  (block = 2 rows, 4 waves = j-quarters)
__global__ __launch_bounds__(256, 2) void fused_kernel(
    const float* __restrict__ x, const int* __restrict__ adj,
    float* __restrict__ T, float* __restrict__ alphaPart,
    float* __restrict__ out) {
    const int N = 1024, D = 64;
    const int t = threadIdx.x;

    __shared__ float4 ti4[32 * 16];  // 8 KB   (phase 2 reuses as part[2][4][64])
    __shared__ float4 tj4[64 * 16];  // 16 KB
    __shared__ float x2i_l[32];
    __shared__ float y2_l[64];

    // ---------------- Phase 1: pair ----------------
    {
        const int jt = blockIdx.x & 15;          // j-tile 0..15
        const int j0 = jt * 64;
        const int i0 = (blockIdx.x >> 4) * 32;   // i-tile 0..31
        const int h = t & 1;     // dim half
        const int q = t >> 1;    // 0..127
        const int qx = q & 15;   // j quad
        const int qy = q >> 4;   // i quad 0..7

        const float4* x4 = reinterpret_cast<const float4*>(x);
#pragma unroll
        for (int k = 0; k < 2; ++k) {
            const int f = k * 256 + t;
            const int r = f >> 4, c = f & 15;
            float4 v = x4[(size_t)i0 * 16 + f];
            ti4[swz(r, c)] = v;
            float s = dot4(v);
#pragma unroll
            for (int off = 1; off <= 8; off <<= 1) s += __shfl_xor(s, off, 64);
            if ((t & 15) == 0) x2i_l[r] = s;
        }
#pragma unroll
        for (int k = 0; k < 4; ++k) {
            const int f = k * 256 + t;
            const int r = f >> 4, c = f & 15;
            float4 v = x4[(size_t)j0 * 16 + f];
            tj4[swz(r, c)] = v;
            float s = dot4(v);
#pragma unroll
            for (int off = 1; off <= 8; off <<= 1) s += __shfl_xor(s, off, 64);
            if ((t & 15) == 0) y2_l[r] = s;
        }
        __syncthreads();

        float acc[4][4];
#pragma unroll
        for (int a = 0; a < 4; ++a)
#pragma unroll
            for (int b = 0; b < 4; ++b) acc[a][b] = 0.f;

#pragma unroll
        for (int cc = 0; cc < 8; ++cc) {
            const int c = h * 8 + cc;
            float4 xiv[4], xjv[4];
#pragma unroll
            for (int a = 0; a < 4; ++a) xiv[a] = ti4[swz(qy * 4 + a, c)];
#pragma unroll
            for (int b = 0; b < 4; ++b) xjv[b] = tj4[swz(qx * 4 + b, c)];
#pragma unroll
            for (int a = 0; a < 4; ++a)
#pragma unroll
                for (int b = 0; b < 4; ++b) {
                    acc[a][b] = fmaf(xiv[a].x, xjv[b].x, acc[a][b]);
                    acc[a][b] = fmaf(xiv[a].y, xjv[b].y, acc[a][b]);
                    acc[a][b] = fmaf(xiv[a].z, xjv[b].z, acc[a][b]);
                    acc[a][b] = fmaf(xiv[a].w, xjv[b].w, acc[a][b]);
                }
        }
        // combine dim-halves
#pragma unroll
        for (int a = 0; a < 4; ++a)
#pragma unroll
            for (int b = 0; b < 4; ++b) acc[a][b] += __shfl_xor(acc[a][b], 1, 64);

        const int ib = i0 + qy * 4;
        const int jb = j0 + qx * 4;
        const int bsel = h * 2;  // this half handles columns jb+bsel, jb+bsel+1
        const float y2[2] = {y2_l[qx * 4 + bsel], y2_l[qx * 4 + bsel + 1]};

        float svsum[4];
#pragma unroll
        for (int a = 0; a < 4; ++a) {
            const int2 aj = *reinterpret_cast<const int2*>(&adj[(size_t)(ib + a) * N + jb + bsel]);
            const int m[2] = {aj.x, aj.y};
            const float x2a = x2i_l[qy * 4 + a];
            const float onemx2 = 1.f - x2a;
            const float onemx2c = fmaxf(onemx2, EPSF);
            float tv2[2];
            float ssum = 0.f;
#pragma unroll
            for (int bb = 0; bb < 2; ++bb) {
                const float dot = acc[a][bsel + bb];
                const float c1 = fmaf(-2.f, dot, 1.f);
                const float A = c1 + y2[bb];
                const float den = fmaxf(fmaf(x2a, y2[bb], c1), EPSF);
                const float rd = rcp_fast(den);
                const float av = -A * rd;
                const float bv = onemx2 * rd;
                float un2 = av * av * x2a;
                un2 = fmaf(bv * bv, y2[bb], un2);
                un2 = fmaf(2.f * av * bv, dot, un2);
                un2 = fmaxf(un2, 0.f);
                float un = sqrtf(un2);
                un = fminf(fmaxf(un, EPSF), 1.0f - 1e-5f);
                const float ratio = (1.f + un) * rcp_fast(1.f - un);
                const float at = 0.34657359027997264f * __log2f(ratio);  // atanh(un)
                const float g = onemx2c * at * rcp_fast(un);
                const float sv = m[bb] ? g * av : 0.f;
                const float tv = m[bb] ? g * bv : 0.f;
                ssum += sv;
                tv2[bb] = tv;
            }
            float2 tw = {tv2[0], tv2[1]};
            *reinterpret_cast<float2*>(&T[(size_t)(ib + a) * N + jb + bsel]) = tw;
            svsum[a] = ssum;
        }

        // reduce alpha over lane bits 0..4 (h + qx)
#pragma unroll
        for (int off = 1; off <= 16; off <<= 1) {
#pragma unroll
            for (int a = 0; a < 4; ++a) svsum[a] += __shfl_xor(svsum[a], off, 64);
        }
        if ((t & 31) == 0) {
#pragma unroll
            for (int a = 0; a < 4; ++a)
                alphaPart[(size_t)jt * N + ib + a] = svsum[a];
        }
    }

    cg::this_grid().sync();  // device-scope fence: T/alphaPart visible across XCDs

    // ---------------- Phase 2: out ----------------
    {
        const int i0 = blockIdx.x * 2;
        const int w = t >> 6;
        const int d = t & 63;
        const int jw = __builtin_amdgcn_readfirstlane(w * 256);

        const float4* T0 = reinterpret_cast<const float4*>(T + (size_t)i0 * N + jw);
        const float4* T1 = reinterpret_cast<const float4*>(T + (size_t)(i0 + 1) * N + jw);
        const float* xbase = x + (size_t)jw * D + d;

        float a0 = 0.f, a1 = 0.f, a2 = 0.f, a3 = 0.f;
        float b0 = 0.f, b1 = 0.f, b2 = 0.f, b3 = 0.f;
#pragma unroll 4
        for (int qq = 0; qq < 64; ++qq) {
            const float4 t0 = T0[qq];
            const float4 t1 = T1[qq];
            const float* xp = xbase + (size_t)qq * 4 * D;
            const float x0 = xp[0 * D], x1 = xp[1 * D], x2v = xp[2 * D], x3 = xp[3 * D];
            a0 = fmaf(t0.x, x0, a0);  b0 = fmaf(t1.x, x0, b0);
            a1 = fmaf(t0.y, x1, a1);  b1 = fmaf(t1.y, x1, b1);
            a2 = fmaf(t0.z, x2v, a2); b2 = fmaf(t1.z, x2v, b2);
            a3 = fmaf(t0.w, x3, a3);  b3 = fmaf(t1.w, x3, b3);
        }

        float (*part)[4][64] = reinterpret_cast<float (*)[4][64]>(ti4);
        part[0][w][d] = (a0 + a1) + (a2 + a3);
        part[1][w][d] = (b0 + b1) + (b2 + b3);
        __syncthreads();

        if (t < 128) {
            const int r = t >> 6;
            const int i = i0 + r;
            float v = (part[r][0][d] + part[r][1][d]) + (part[r][2][d] + part[r][3][d]);

            // alpha = sum of 16 j-tile partials
            float ap = (d < 16) ? alphaPart[(size_t)d * N + i] : 0.f;
#pragma unroll
            for (int off = 1; off < 64; off <<= 1) ap += __shfl_xor(ap, off, 64);

            const float xid = x[(size_t)i * D + d];
            float x2i = xid * xid;
#pragma unroll
            for (int off = 1; off < 64; off <<= 1) x2i += __shfl_xor(x2i, off, 64);
            const float onemx2 = 1.f - x2i;
            const float onemx2c = fmaxf(onemx2, EPSF);
            v = fmaf(ap, xid, v);

            // expmap(v, x_i)
            float vn2 = v * v;
#pragma unroll
            for (int off = 1; off < 64; off <<= 1) vn2 += __shfl_xor(vn2, off, 64);
            const float vn = fmaxf(sqrtf(vn2), EPSF);
            const float arg = vn * rcp_fast(onemx2c);
            const float th = tanhf(arg);
            const float sec = th * rcp_fast(vn) * v;

            // mobius_add(x_i, sec)
            float xy = xid * sec;
            float y2p = sec * sec;
#pragma unroll
            for (int off = 1; off < 64; off <<= 1) {
                xy += __shfl_xor(xy, off, 64);
                y2p += __shfl_xor(y2p, off, 64);
            }
            const float numd = (1.f + 2.f * xy + y2p) * xid + onemx2 * sec;
            const float den2 = fmaxf(fmaf(x2i, y2p, 1.f + 2.f * xy), EPSF);
            out[(size_t)i * D + d] = numd * rcp_fast(den2);
        }
    }
}

extern "C" void kernel_launch(void* const* d_in, const int* in_sizes, int n_in,
                              void* d_out, int out_size, void* d_ws, size_t ws_size,
                              hipStream_t stream) {
    const float* x = (const float*)d_in[0];
    const int* adj = (const int*)d_in[1];
    float* out = (float*)d_out;
    const int N = 1024;

    float* T = (float*)d_ws;                                       // 4 MB
    float* alphaPart = (float*)((char*)d_ws + (size_t)N * N * 4);  // 64 KB

    void* args[] = {(void*)&x, (void*)&adj, (void*)&T, (void*)&alphaPart, (void*)&out};
    hipLaunchCooperativeKernel((const void*)fused_kernel, dim3(512), dim3(256),
                               args, 0, stream);
}

// Round 9
// 20.390 us; speedup vs baseline: 4.4659x; 4.4659x over previous
//
#include <hip/hip_runtime.h>

#define EPSF 1e-7f

__device__ __forceinline__ float rcp_fast(float x) { return __builtin_amdgcn_rcpf(x); }

// LDS float4-chunk swizzle: spreads strided row reads across bank groups.
__device__ __forceinline__ int swz(int r, int c) { return r * 16 + (c ^ ((r >> 2) & 7)); }

__device__ __forceinline__ float dot4(float4 v) {
    return v.x * v.x + v.y * v.y + v.z * v.z + v.w * v.w;
}

// K1: 32(i) x 64(j) tile per block, 512 blocks x 256 threads = 2 waves/SIMD.
// Lane-pair micro-tile: thread (q,h) computes 4x4 half-dots over dims [h*32,h*32+32),
// shfl_xor(1) combines; halves split the 16-pair scalar map (8 pairs each).
__global__ __launch_bounds__(256, 2) void pair_kernel(
    const float* __restrict__ x, const int* __restrict__ adj,
    float* __restrict__ T, float* __restrict__ alphaPart) {
    const int N = 1024;
    const int j0 = blockIdx.x * 64;
    const int i0 = blockIdx.y * 32;
    const int t = threadIdx.x;
    const int h = t & 1;     // dim half
    const int q = t >> 1;    // 0..127
    const int qx = q & 15;   // j quad
    const int qy = q >> 4;   // i quad 0..7

    __shared__ float4 ti4[32 * 16];  // 8 KB
    __shared__ float4 tj4[64 * 16];  // 16 KB
    __shared__ float x2i_l[32];
    __shared__ float y2_l[64];

    const float4* x4 = reinterpret_cast<const float4*>(x);
#pragma unroll
    for (int k = 0; k < 2; ++k) {
        const int f = k * 256 + t;
        const int r = f >> 4, c = f & 15;
        float4 v = x4[(size_t)i0 * 16 + f];
        ti4[swz(r, c)] = v;
        float s = dot4(v);
#pragma unroll
        for (int off = 1; off <= 8; off <<= 1) s += __shfl_xor(s, off, 64);
        if ((t & 15) == 0) x2i_l[r] = s;
    }
#pragma unroll
    for (int k = 0; k < 4; ++k) {
        const int f = k * 256 + t;
        const int r = f >> 4, c = f & 15;
        float4 v = x4[(size_t)j0 * 16 + f];
        tj4[swz(r, c)] = v;
        float s = dot4(v);
#pragma unroll
        for (int off = 1; off <= 8; off <<= 1) s += __shfl_xor(s, off, 64);
        if ((t & 15) == 0) y2_l[r] = s;
    }
    __syncthreads();

    float acc[4][4];
#pragma unroll
    for (int a = 0; a < 4; ++a)
#pragma unroll
        for (int b = 0; b < 4; ++b) acc[a][b] = 0.f;

#pragma unroll
    for (int cc = 0; cc < 8; ++cc) {
        const int c = h * 8 + cc;
        float4 xiv[4], xjv[4];
#pragma unroll
        for (int a = 0; a < 4; ++a) xiv[a] = ti4[swz(qy * 4 + a, c)];
#pragma unroll
        for (int b = 0; b < 4; ++b) xjv[b] = tj4[swz(qx * 4 + b, c)];
#pragma unroll
        for (int a = 0; a < 4; ++a)
#pragma unroll
            for (int b = 0; b < 4; ++b) {
                acc[a][b] = fmaf(xiv[a].x, xjv[b].x, acc[a][b]);
                acc[a][b] = fmaf(xiv[a].y, xjv[b].y, acc[a][b]);
                acc[a][b] = fmaf(xiv[a].z, xjv[b].z, acc[a][b]);
                acc[a][b] = fmaf(xiv[a].w, xjv[b].w, acc[a][b]);
            }
    }
    // combine dim-halves: both lanes end with full 64-dim dots
#pragma unroll
    for (int a = 0; a < 4; ++a)
#pragma unroll
        for (int b = 0; b < 4; ++b) acc[a][b] += __shfl_xor(acc[a][b], 1, 64);

    const int ib = i0 + qy * 4;
    const int jb = j0 + qx * 4;
    const int bsel = h * 2;  // this half handles columns jb+bsel, jb+bsel+1
    const float y2[2] = {y2_l[qx * 4 + bsel], y2_l[qx * 4 + bsel + 1]};

    float svsum[4];
#pragma unroll
    for (int a = 0; a < 4; ++a) {
        const int2 aj = *reinterpret_cast<const int2*>(&adj[(size_t)(ib + a) * N + jb + bsel]);
        const int m[2] = {aj.x, aj.y};
        const float x2a = x2i_l[qy * 4 + a];
        const float onemx2 = 1.f - x2a;
        const float onemx2c = fmaxf(onemx2, EPSF);
        float tv2[2];
        float ssum = 0.f;
#pragma unroll
        for (int bb = 0; bb < 2; ++bb) {
            const float dot = acc[a][bsel + bb];
            const float c1 = fmaf(-2.f, dot, 1.f);
            const float A = c1 + y2[bb];
            const float den = fmaxf(fmaf(x2a, y2[bb], c1), EPSF);
            const float rd = rcp_fast(den);
            const float av = -A * rd;
            const float bv = onemx2 * rd;
            float un2 = av * av * x2a;
            un2 = fmaf(bv * bv, y2[bb], un2);
            un2 = fmaf(2.f * av * bv, dot, un2);
            un2 = fmaxf(un2, 0.f);
            float un = sqrtf(un2);
            un = fminf(fmaxf(un, EPSF), 1.0f - 1e-5f);
            const float ratio = (1.f + un) * rcp_fast(1.f - un);
            const float at = 0.34657359027997264f * __log2f(ratio);  // atanh(un)
            const float g = onemx2c * at * rcp_fast(un);
            const float sv = m[bb] ? g * av : 0.f;
            const float tv = m[bb] ? g * bv : 0.f;
            ssum += sv;
            tv2[bb] = tv;
        }
        float2 tw = {tv2[0], tv2[1]};
        *reinterpret_cast<float2*>(&T[(size_t)(ib + a) * N + jb + bsel]) = tw;
        svsum[a] = ssum;
    }

    // reduce alpha over lane bits 0..4 (h + qx)
#pragma unroll
    for (int off = 1; off <= 16; off <<= 1) {
#pragma unroll
        for (int a = 0; a < 4; ++a) svsum[a] += __shfl_xor(svsum[a], off, 64);
    }
    if ((t & 31) == 0) {
#pragma unroll
        for (int a = 0; a < 4; ++a)
            alphaPart[(size_t)blockIdx.x * N + ib + a] = svsum[a];
    }
}

// K2: block = 4 rows, 256 blocks x 512 thr (8 waves) = 2 waves/SIMD.
// Wave w owns j-chunk [w*128, w*128+128); T row bases scalar (readfirstlane);
// each x load feeds 4 rows. x traffic: 256 blocks x 256KB = 64 MB (halved).
__global__ __launch_bounds__(512, 2) void out_kernel(
    const float* __restrict__ x, const float* __restrict__ T,
    const float* __restrict__ alphaPart, float* __restrict__ out) {
    const int N = 1024, D = 64;
    const int i0 = blockIdx.x * 4;
    const int w = threadIdx.x >> 6;     // 0..7
    const int d = threadIdx.x & 63;
    const int jw = __builtin_amdgcn_readfirstlane(w * 128);

    const float4* T0 = reinterpret_cast<const float4*>(T + (size_t)(i0 + 0) * N + jw);
    const float4* T1 = reinterpret_cast<const float4*>(T + (size_t)(i0 + 1) * N + jw);
    const float4* T2 = reinterpret_cast<const float4*>(T + (size_t)(i0 + 2) * N + jw);
    const float4* T3 = reinterpret_cast<const float4*>(T + (size_t)(i0 + 3) * N + jw);
    const float* xbase = x + (size_t)jw * D + d;

    float acc[4][4];
#pragma unroll
    for (int r = 0; r < 4; ++r)
#pragma unroll
        for (int c = 0; c < 4; ++c) acc[r][c] = 0.f;

#pragma unroll 4
    for (int q = 0; q < 32; ++q) {  // 128 j per wave, 4 per iter
        const float4 tq[4] = {T0[q], T1[q], T2[q], T3[q]};
        const float* xp = xbase + (size_t)q * 4 * D;
        const float x0 = xp[0 * D], x1 = xp[1 * D], x2v = xp[2 * D], x3 = xp[3 * D];
#pragma unroll
        for (int r = 0; r < 4; ++r) {
            acc[r][0] = fmaf(tq[r].x, x0, acc[r][0]);
            acc[r][1] = fmaf(tq[r].y, x1, acc[r][1]);
            acc[r][2] = fmaf(tq[r].z, x2v, acc[r][2]);
            acc[r][3] = fmaf(tq[r].w, x3, acc[r][3]);
        }
    }

    __shared__ float part[4][8][64];  // 8 KB
#pragma unroll
    for (int r = 0; r < 4; ++r)
        part[r][w][d] = (acc[r][0] + acc[r][1]) + (acc[r][2] + acc[r][3]);
    __syncthreads();

    if (threadIdx.x < 256) {
        const int r = threadIdx.x >> 6;  // wave r handles row i0+r
        const int i = i0 + r;
        float v = 0.f;
#pragma unroll
        for (int ww = 0; ww < 8; ++ww) v += part[r][ww][d];

        // alpha = sum of 16 j-tile partials
        float ap = (d < 16) ? alphaPart[(size_t)d * N + i] : 0.f;
#pragma unroll
        for (int off = 1; off < 64; off <<= 1) ap += __shfl_xor(ap, off, 64);

        const float xid = x[(size_t)i * D + d];
        float x2i = xid * xid;
#pragma unroll
        for (int off = 1; off < 64; off <<= 1) x2i += __shfl_xor(x2i, off, 64);
        const float onemx2 = 1.f - x2i;
        const float onemx2c = fmaxf(onemx2, EPSF);
        v = fmaf(ap, xid, v);

        // expmap(v, x_i)
        float vn2 = v * v;
#pragma unroll
        for (int off = 1; off < 64; off <<= 1) vn2 += __shfl_xor(vn2, off, 64);
        const float vn = fmaxf(sqrtf(vn2), EPSF);
        const float arg = vn * rcp_fast(onemx2c);
        const float th = tanhf(arg);
        const float sec = th * rcp_fast(vn) * v;

        // mobius_add(x_i, sec)
        float xy = xid * sec;
        float y2p = sec * sec;
#pragma unroll
        for (int off = 1; off < 64; off <<= 1) {
            xy += __shfl_xor(xy, off, 64);
            y2p += __shfl_xor(y2p, off, 64);
        }
        const float numd = (1.f + 2.f * xy + y2p) * xid + onemx2 * sec;
        const float den2 = fmaxf(fmaf(x2i, y2p, 1.f + 2.f * xy), EPSF);
        out[(size_t)i * D + d] = numd * rcp_fast(den2);
    }
}

extern "C" void kernel_launch(void* const* d_in, const int* in_sizes, int n_in,
                              void* d_out, int out_size, void* d_ws, size_t ws_size,
                              hipStream_t stream) {
    const float* x = (const float*)d_in[0];
    const int* adj = (const int*)d_in[1];
    float* out = (float*)d_out;
    const int N = 1024;

    float* T = (float*)d_ws;                                       // 4 MB
    float* alphaPart = (float*)((char*)d_ws + (size_t)N * N * 4);  // 64 KB

    hipLaunchKernelGGL(pair_kernel, dim3(16, 32), dim3(256), 0, stream, x, adj, T, alphaPart);
    hipLaunchKernelGGL(out_kernel, dim3(N / 4), dim3(512), 0, stream, x, T, alphaPart, out);
}

// Round 10
// 19.523 us; speedup vs baseline: 4.6642x; 1.0444x over previous
//
#include <hip/hip_runtime.h>

#define EPSF 1e-7f

__device__ __forceinline__ float rcp_fast(float x) { return __builtin_amdgcn_rcpf(x); }

// LDS float4-chunk swizzle: spreads strided row reads across bank groups.
__device__ __forceinline__ int swz(int r, int c) { return r * 16 + (c ^ ((r >> 2) & 7)); }

__device__ __forceinline__ float dot4(float4 v) {
    return v.x * v.x + v.y * v.y + v.z * v.z + v.w * v.w;
}

// K1: 32(i) x 64(j) tile, 512 blocks x 512 threads = 4 waves/SIMD.
// Lane-quad micro-tile: thread (q, h2) computes 4x4 quarter-dots over dims
// [h2*16, h2*16+16); shfl_xor(1),(2) combine; lane h2 evaluates col jb+h2 for
// its 4 rows. LDS read volume identical to round-7 (ratio 8 FMA per b128).
__global__ __launch_bounds__(512, 4) void pair_kernel(
    const float* __restrict__ x, const int* __restrict__ adj,
    float* __restrict__ T, float* __restrict__ alphaPart) {
    const int N = 1024;
    const int j0 = blockIdx.x * 64;
    const int i0 = blockIdx.y * 32;
    const int t = threadIdx.x;       // 0..511
    const int h2 = t & 3;            // dim quarter / col select
    const int q = t >> 2;            // 0..127
    const int qx = q & 15;           // j quad
    const int qy = q >> 4;           // 0..7, 4-row group

    __shared__ float4 ti4[32 * 16];  // 8 KB
    __shared__ float4 tj4[64 * 16];  // 16 KB
    __shared__ float x2i_l[32];
    __shared__ float y2_l[64];

    const float4* x4 = reinterpret_cast<const float4*>(x);
    {   // ti: 512 float4, one pass
        const int r = t >> 4, c = t & 15;
        float4 v = x4[(size_t)i0 * 16 + t];
        ti4[swz(r, c)] = v;
        float s = dot4(v);
#pragma unroll
        for (int off = 1; off <= 8; off <<= 1) s += __shfl_xor(s, off, 64);
        if ((t & 15) == 0) x2i_l[r] = s;
    }
#pragma unroll
    for (int k = 0; k < 2; ++k) {  // tj: 1024 float4, two passes
        const int f = k * 512 + t;
        const int r = f >> 4, c = f & 15;
        float4 v = x4[(size_t)j0 * 16 + f];
        tj4[swz(r, c)] = v;
        float s = dot4(v);
#pragma unroll
        for (int off = 1; off <= 8; off <<= 1) s += __shfl_xor(s, off, 64);
        if ((t & 15) == 0) y2_l[r] = s;
    }
    __syncthreads();

    float acc[4][4];
#pragma unroll
    for (int a = 0; a < 4; ++a)
#pragma unroll
        for (int b = 0; b < 4; ++b) acc[a][b] = 0.f;

#pragma unroll
    for (int cc = 0; cc < 4; ++cc) {
        const int c = h2 * 4 + cc;
        float4 xiv[4], xjv[4];
#pragma unroll
        for (int a = 0; a < 4; ++a) xiv[a] = ti4[swz(qy * 4 + a, c)];
#pragma unroll
        for (int b = 0; b < 4; ++b) xjv[b] = tj4[swz(qx * 4 + b, c)];
#pragma unroll
        for (int a = 0; a < 4; ++a)
#pragma unroll
            for (int b = 0; b < 4; ++b) {
                acc[a][b] = fmaf(xiv[a].x, xjv[b].x, acc[a][b]);
                acc[a][b] = fmaf(xiv[a].y, xjv[b].y, acc[a][b]);
                acc[a][b] = fmaf(xiv[a].z, xjv[b].z, acc[a][b]);
                acc[a][b] = fmaf(xiv[a].w, xjv[b].w, acc[a][b]);
            }
    }
    // combine dim-quarters (lane bits 0,1): all quad lanes end with full dots
#pragma unroll
    for (int a = 0; a < 4; ++a)
#pragma unroll
        for (int b = 0; b < 4; ++b) {
            acc[a][b] += __shfl_xor(acc[a][b], 1, 64);
            acc[a][b] += __shfl_xor(acc[a][b], 2, 64);
        }

    const int ib = i0 + qy * 4;
    const int jb = j0 + qx * 4;
    const int jcol = jb + h2;        // this lane's column
    const float y2c = y2_l[qx * 4 + h2];

    float svsum[4];
#pragma unroll
    for (int a = 0; a < 4; ++a) {
        const int m = adj[(size_t)(ib + a) * N + jcol];
        const float x2a = x2i_l[qy * 4 + a];
        const float onemx2 = 1.f - x2a;
        const float onemx2c = fmaxf(onemx2, EPSF);
        const float dot = acc[a][h2];
        const float c1 = fmaf(-2.f, dot, 1.f);
        const float A = c1 + y2c;
        const float den = fmaxf(fmaf(x2a, y2c, c1), EPSF);
        const float rd = rcp_fast(den);
        const float av = -A * rd;
        const float bv = onemx2 * rd;
        float un2 = av * av * x2a;
        un2 = fmaf(bv * bv, y2c, un2);
        un2 = fmaf(2.f * av * bv, dot, un2);
        un2 = fmaxf(un2, 0.f);
        float un = sqrtf(un2);
        un = fminf(fmaxf(un, EPSF), 1.0f - 1e-5f);
        const float ratio = (1.f + un) * rcp_fast(1.f - un);
        const float at = 0.34657359027997264f * __log2f(ratio);  // atanh(un)
        const float g = onemx2c * at * rcp_fast(un);
        const float sv = m ? g * av : 0.f;
        const float tv = m ? g * bv : 0.f;
        T[(size_t)(ib + a) * N + jcol] = tv;
        svsum[a] = sv;
    }

    // each wave owns one 4-row group x all 64 j: full-wave butterfly
#pragma unroll
    for (int off = 1; off < 64; off <<= 1) {
#pragma unroll
        for (int a = 0; a < 4; ++a) svsum[a] += __shfl_xor(svsum[a], off, 64);
    }
    if ((t & 63) == 0) {
#pragma unroll
        for (int a = 0; a < 4; ++a)
            alphaPart[(size_t)blockIdx.x * N + ib + a] = svsum[a];
    }
}

// K2: block = 4 rows, 256 blocks x 1024 thr (16 waves, 1 block/CU = 4 waves/SIMD).
// Wave w owns j-chunk [w*64, w*64+64); T row bases scalar (readfirstlane);
// each x load feeds 4 rows. x traffic 64 MB via L2.
__global__ __launch_bounds__(1024, 4) void out_kernel(
    const float* __restrict__ x, const float* __restrict__ T,
    const float* __restrict__ alphaPart, float* __restrict__ out) {
    const int N = 1024, D = 64;
    const int i0 = blockIdx.x * 4;
    const int w = threadIdx.x >> 6;     // 0..15
    const int d = threadIdx.x & 63;
    const int jw = __builtin_amdgcn_readfirstlane(w * 64);

    const float4* T0 = reinterpret_cast<const float4*>(T + (size_t)(i0 + 0) * N + jw);
    const float4* T1 = reinterpret_cast<const float4*>(T + (size_t)(i0 + 1) * N + jw);
    const float4* T2 = reinterpret_cast<const float4*>(T + (size_t)(i0 + 2) * N + jw);
    const float4* T3 = reinterpret_cast<const float4*>(T + (size_t)(i0 + 3) * N + jw);
    const float* xbase = x + (size_t)jw * D + d;

    float acc[4][4];
#pragma unroll
    for (int r = 0; r < 4; ++r)
#pragma unroll
        for (int c = 0; c < 4; ++c) acc[r][c] = 0.f;

#pragma unroll 4
    for (int q = 0; q < 16; ++q) {  // 64 j per wave, 4 per iter
        const float4 tq[4] = {T0[q], T1[q], T2[q], T3[q]};
        const float* xp = xbase + (size_t)q * 4 * D;
        const float x0 = xp[0 * D], x1 = xp[1 * D], x2v = xp[2 * D], x3 = xp[3 * D];
#pragma unroll
        for (int r = 0; r < 4; ++r) {
            acc[r][0] = fmaf(tq[r].x, x0, acc[r][0]);
            acc[r][1] = fmaf(tq[r].y, x1, acc[r][1]);
            acc[r][2] = fmaf(tq[r].z, x2v, acc[r][2]);
            acc[r][3] = fmaf(tq[r].w, x3, acc[r][3]);
        }
    }

    __shared__ float part[4][16][64];  // 16 KB
#pragma unroll
    for (int r = 0; r < 4; ++r)
        part[r][w][d] = (acc[r][0] + acc[r][1]) + (acc[r][2] + acc[r][3]);
    __syncthreads();

    if (threadIdx.x < 256) {
        const int r = threadIdx.x >> 6;  // wave r handles row i0+r
        const int i = i0 + r;
        float v = 0.f;
#pragma unroll
        for (int ww = 0; ww < 16; ++ww) v += part[r][ww][d];

        // alpha = sum of 16 j-tile partials
        float ap = (d < 16) ? alphaPart[(size_t)d * N + i] : 0.f;
#pragma unroll
        for (int off = 1; off < 64; off <<= 1) ap += __shfl_xor(ap, off, 64);

        const float xid = x[(size_t)i * D + d];
        float x2i = xid * xid;
#pragma unroll
        for (int off = 1; off < 64; off <<= 1) x2i += __shfl_xor(x2i, off, 64);
        const float onemx2 = 1.f - x2i;
        const float onemx2c = fmaxf(onemx2, EPSF);
        v = fmaf(ap, xid, v);

        // expmap(v, x_i)
        float vn2 = v * v;
#pragma unroll
        for (int off = 1; off < 64; off <<= 1) vn2 += __shfl_xor(vn2, off, 64);
        const float vn = fmaxf(sqrtf(vn2), EPSF);
        const float arg = vn * rcp_fast(onemx2c);
        const float th = tanhf(arg);
        const float sec = th * rcp_fast(vn) * v;

        // mobius_add(x_i, sec)
        float xy = xid * sec;
        float y2p = sec * sec;
#pragma unroll
        for (int off = 1; off < 64; off <<= 1) {
            xy += __shfl_xor(xy, off, 64);
            y2p += __shfl_xor(y2p, off, 64);
        }
        const float numd = (1.f + 2.f * xy + y2p) * xid + onemx2 * sec;
        const float den2 = fmaxf(fmaf(x2i, y2p, 1.f + 2.f * xy), EPSF);
        out[(size_t)i * D + d] = numd * rcp_fast(den2);
    }
}

extern "C" void kernel_launch(void* const* d_in, const int* in_sizes, int n_in,
                              void* d_out, int out_size, void* d_ws, size_t ws_size,
                              hipStream_t stream) {
    const float* x = (const float*)d_in[0];
    const int* adj = (const int*)d_in[1];
    float* out = (float*)d_out;
    const int N = 1024;

    float* T = (float*)d_ws;                                       // 4 MB
    float* alphaPart = (float*)((char*)d_ws + (size_t)N * N * 4);  // 64 KB

    hipLaunchKernelGGL(pair_kernel, dim3(16, 32), dim3(512), 0, stream, x, adj, T, alphaPart);
    hipLaunchKernelGGL(out_kernel, dim3(N / 4), dim3(1024), 0, stream, x, T, alphaPart, out);
}